// Round 11
// baseline (274.399 us; speedup 1.0000x reference)
//
#include <hip/hip_runtime.h>
#include <hip/hip_bf16.h>
#include <stdint.h>

// ---------------------------------------------------------------------------
// SelectiveMixing: x->W1->silu->W2->(q,k,g); v=(x@Wv+bv)*sig(g);
// attn=softmax(qk^T/sqrt(D)); out=rmsnorm(mix*attn@v + (1-mix)*x)
// B=4, L=2048, D=1024, INNER=1536. bf16 MFMA, f32 accum.
// Softmax fused: P' = exp(min(s,80)) bf16 + f32 row sums (atomics); PV
// applies 1/l; fused mix+rmsnorm finishes.
// gemm8<EPI>: m201-style 8-phase 256x256 GEMM (wave tile 128x64, B
//   reg-cached, counted vmcnt(4) at phases 4/8) — GEMM2 (EPI 1) + scores
//   (EPI 5). gemm5<EPI>: 256x128 4-phase GEMM — GEMM1, VGEMM, PV.
// RULE: inside counted-vmcnt regions NO other VMEM op may issue.
// ---------------------------------------------------------------------------

typedef __bf16 bf16x8 __attribute__((ext_vector_type(8)));
typedef float f32x4 __attribute__((ext_vector_type(4)));

#define VM4 asm volatile("s_waitcnt vmcnt(4)" ::: "memory")
#define VM2 asm volatile("s_waitcnt vmcnt(2)" ::: "memory")
#define VM0 asm volatile("s_waitcnt vmcnt(0)" ::: "memory")
#define LGKM0 asm volatile("s_waitcnt lgkmcnt(0)" ::: "memory")
#define BAR __builtin_amdgcn_s_barrier()
#define SCB __builtin_amdgcn_sched_barrier(0)

__device__ __forceinline__ unsigned short f2bf(float f) {
    unsigned int u = __float_as_uint(f);
    u += 0x7fffu + ((u >> 16) & 1u);
    return (unsigned short)(u >> 16);
}
__device__ __forceinline__ float bf2f(unsigned short s) {
    return __uint_as_float(((unsigned int)s) << 16);
}
__device__ __forceinline__ void llds16(const void* g, void* l) {
    __builtin_amdgcn_global_load_lds(
        (const __attribute__((address_space(1))) void*)g,
        (__attribute__((address_space(3))) void*)l, 16, 0, 0);
}
__device__ __forceinline__ f32x4 MF(bf16x8 a, bf16x8 b, f32x4 c) {
    return __builtin_amdgcn_mfma_f32_16x16x32_bf16(a, b, c, 0, 0, 0);
}

// ---------------- zero fill ------------------------------------------------
__global__ __launch_bounds__(256) void zero_f32(float* __restrict__ p, int n) {
    int i = blockIdx.x * 256 + threadIdx.x;
    if (i < n) p[i] = 0.f;
}

// ---------------- elementwise: f32 -> bf16 (8 elems/thread) ----------------
__global__ __launch_bounds__(256) void cvt_f32_bf16(
    const float* __restrict__ in, unsigned short* __restrict__ out, long long n8) {
    long long i = (long long)blockIdx.x * 256 + threadIdx.x;
    if (i >= n8) return;
    float4 a = ((const float4*)in)[2 * i];
    float4 b = ((const float4*)in)[2 * i + 1];
    ushort4 p0, p1;
    p0.x = f2bf(a.x); p0.y = f2bf(a.y); p0.z = f2bf(a.z); p0.w = f2bf(a.w);
    p1.x = f2bf(b.x); p1.y = f2bf(b.y); p1.z = f2bf(b.z); p1.w = f2bf(b.w);
    ((ushort4*)out)[2 * i] = p0;
    ((ushort4*)out)[2 * i + 1] = p1;
}

// ---------------- transpose + convert: f32 [R][C] -> bf16 [C][R] -----------
__global__ __launch_bounds__(256) void transpose_cvt(
    const float* __restrict__ in, unsigned short* __restrict__ out, int R, int C) {
    __shared__ unsigned short tile[32][33];
    int c0 = blockIdx.x * 32, r0 = blockIdx.y * 32;
    int cc = threadIdx.x & 31, rr = threadIdx.x >> 5;
#pragma unroll
    for (int p = 0; p < 4; ++p) {
        int r = rr + p * 8;
        tile[r][cc] = f2bf(in[(size_t)(r0 + r) * C + c0 + cc]);
    }
    __syncthreads();
#pragma unroll
    for (int p = 0; p < 4; ++p) {
        int c = rr + p * 8;
        out[(size_t)(c0 + c) * R + r0 + cc] = tile[cc][c];
    }
}

// ---------------- gemm8: 8-phase 256x256 GEMM, C = A @ B^T -----------------
// 512 threads = 8 waves (2M x 4N), wave tile 128x64, BK=64.
// LDS: 2 buffers x (A 256x64 + B 256x64) bf16 = 128 KiB, XOR-swizzled.
// Per K-tile: 4 phases; phase q reads A M-frags {2q,2q+1}; at q==0 all 8 B
// frags (reg-cached for the tile). Each phase stages one half-tile per the
// FIFO ledger (see round-8 comment). vmcnt(4) at phase 4/8 end; last
// iteration: vmcnt(0) at phase 4, nothing outstanding at phase 8.
// EPI 1: bf16 = acc + bias[n]
// EPI 5: P' bf16 = exp(min(acc*scale,80)); atomicAdd row sums into stat.
template <int EPI>
__global__ __launch_bounds__(512, 1) void gemm8(
    const unsigned short* __restrict__ A, int lda, long long Abs,
    const unsigned short* __restrict__ B, int ldb, long long Bbs,
    int K,
    unsigned short* __restrict__ out, int ldo, long long Obs,
    float scale, int gx, float* __restrict__ stat,
    const float* __restrict__ bias) {
    __shared__ unsigned short lds[65536];  // X @0, Y @32768
    const int tid = threadIdx.x, lane = tid & 63, wid = tid >> 6;
    const int wr = wid >> 2, wc = wid & 3;  // 2M x 4N
    const int nwg = gridDim.x;
    const int bswz = ((int)blockIdx.x & 7) * (nwg >> 3) + ((int)blockIdx.x >> 3);
    const int bx = bswz % gx, by = bswz / gx;
    const int bm = by * 256, bn = bx * 256;
    const int z = blockIdx.z;
    A += (long long)z * Abs;
    B += (long long)z * Bbs;
    const int NT = K >> 6;  // even, >= 4

    const int sswz = ((tid & 7) ^ ((tid >> 3) & 7)) * 8;
    size_t agc[4], bgc[4];
#pragma unroll
    for (int c = 0; c < 4; ++c) {
        agc[c] = (size_t)(bm + c * 64 + (tid >> 3)) * lda + sswz;
        bgc[c] = (size_t)(bn + c * 64 + (tid >> 3)) * ldb + sswz;
    }
    const int wl = wid * 512;

    auto stA = [&](int t, int h, int buf) {
        const size_t k0 = (size_t)t << 6;
        llds16(A + agc[h * 2] + k0, &lds[buf + (h * 2) * 4096 + wl]);
        llds16(A + agc[h * 2 + 1] + k0, &lds[buf + (h * 2 + 1) * 4096 + wl]);
    };
    auto stB = [&](int t, int h, int buf) {
        const size_t k0 = (size_t)t << 6;
        llds16(B + bgc[h * 2] + k0, &lds[buf + 16384 + (h * 2) * 4096 + wl]);
        llds16(B + bgc[h * 2 + 1] + k0,
               &lds[buf + 16384 + (h * 2 + 1) * 4096 + wl]);
    };

    const int l15 = lane & 15, g4 = lane >> 4, l7 = lane & 7;
    const int x0 = (g4 ^ l7) * 8, x1 = ((4 + g4) ^ l7) * 8;
    const int ab = (wr * 128 + l15) * 64;           // A: + m*1024 + xs
    const int bbv = 16384 + (wc * 64 + l15) * 64;   // B: + j*1024 + xs
    constexpr int X = 0, Y = 32768;

    f32x4 acc[8][4] = {};

    // prologue: A(0),B(0) -> X; B(1) -> Y. vmcnt(4) leaves B(1) in flight.
    stA(0, 0, X); stA(0, 1, X); stB(0, 0, X); stB(0, 1, X);
    stB(1, 0, Y); stB(1, 1, Y);
    VM4;
    BAR; SCB;

    int t = 0;
    while (true) {
        const bool st2 = (t + 2) < NT;
#pragma unroll
        for (int hb = 0; hb < 2; ++hb) {
            const int buf = hb ? Y : X;
            bf16x8 bfr[4][2];
#pragma unroll
            for (int q = 0; q < 4; ++q) {
                // ---- ds reads for this phase
                if (q == 0) {
#pragma unroll
                    for (int j = 0; j < 4; ++j) {
                        bfr[j][0] = *(const bf16x8*)&lds[buf + bbv + j * 1024 + x0];
                        bfr[j][1] = *(const bf16x8*)&lds[buf + bbv + j * 1024 + x1];
                    }
                }
                bf16x8 af[2][2];
#pragma unroll
                for (int mq = 0; mq < 2; ++mq) {
                    af[mq][0] =
                        *(const bf16x8*)&lds[buf + ab + (q * 2 + mq) * 1024 + x0];
                    af[mq][1] =
                        *(const bf16x8*)&lds[buf + ab + (q * 2 + mq) * 1024 + x1];
                }
                // ---- stage one half-tile (FIFO ledger)
                if (hb == 0) {
                    if (q == 0) stA(t + 1, 0, Y);
                    else if (q == 1) stA(t + 1, 1, Y);
                    else if (q == 2) { if (st2) stB(t + 2, 0, X); }
                    else { if (st2) stB(t + 2, 1, X); }
                } else {
                    if (q == 0) { if (st2) stA(t + 2, 0, X); }
                    else if (q == 1) { if (st2) stA(t + 2, 1, X); }
                    else if (q == 2) { if (st2) stB(t + 3, 0, Y); }
                    else { if (st2) stB(t + 3, 1, Y); }
                }
                BAR;
                LGKM0; SCB;
                __builtin_amdgcn_s_setprio(1);
#pragma unroll
                for (int s = 0; s < 2; ++s)
#pragma unroll
                    for (int mq = 0; mq < 2; ++mq)
#pragma unroll
                        for (int j = 0; j < 4; ++j)
                            acc[q * 2 + mq][j] =
                                MF(af[mq][s], bfr[j][s], acc[q * 2 + mq][j]);
                __builtin_amdgcn_s_setprio(0);
                if (q == 3) {
                    if (hb == 0) { if (st2) { VM4; } else { VM0; } }
                    else if (st2) { VM4; }
                }
                if (hb == 1 && q == 3 && !st2) break;  // done; nothing in flight
                BAR; SCB;
            }
        }
        if (!st2) break;
        t += 2;
    }

    // --- epilogue (all global reads AFTER the final "memory" asm)
    const int row0 = bm + wr * 128, col0 = bn + wc * 64;
    unsigned short* o = out + (size_t)z * Obs;
    if constexpr (EPI == 1) {
#pragma unroll
        for (int m = 0; m < 8; ++m) {
            const int mb = row0 + m * 16 + g4 * 4;
#pragma unroll
            for (int j = 0; j < 4; ++j) {
                const int n = col0 + j * 16 + l15;
                const float bs = bias[n];
#pragma unroll
                for (int qq = 0; qq < 4; ++qq)
                    o[(size_t)(mb + qq) * ldo + n] = f2bf(acc[m][j][qq] + bs);
            }
        }
    } else {  // EPI == 5
#pragma unroll
        for (int m = 0; m < 8; ++m) {
            const int mb = row0 + m * 16 + g4 * 4;
            float rs[4] = {0.f, 0.f, 0.f, 0.f};
#pragma unroll
            for (int j = 0; j < 4; ++j) {
                const int n = col0 + j * 16 + l15;
#pragma unroll
                for (int qq = 0; qq < 4; ++qq) {
                    float p = __expf(fminf(acc[m][j][qq] * scale, 80.f));
                    o[(size_t)(mb + qq) * ldo + n] = f2bf(p);
                    rs[qq] += p;
                }
            }
#pragma unroll
            for (int qq = 0; qq < 4; ++qq) {
                float s = rs[qq];
                s += __shfl_xor(s, 1); s += __shfl_xor(s, 2);
                s += __shfl_xor(s, 4); s += __shfl_xor(s, 8);
                if (l15 == 0) atomicAdd(&stat[(size_t)z * 2048 + mb + qq], s);
            }
        }
    }
}

// ---------------- gemm5: 256x128 pipelined GEMM, C = A @ B^T ---------------
// EPI 1: bf16 = acc+bias[n]
// EPI 0: bf16 = silu(acc+bias[n])
// EPI 2: vT bf16: out[(m>>11)*1024+n][m&2047] = (acc+bias[n])*sigmoid(gate)
// EPI 6: gi bf16 = acc / l[row]
template <int EPI>
__global__ __launch_bounds__(512, 1) void gemm5(
    const unsigned short* __restrict__ A, int lda, long long Abs,
    const unsigned short* __restrict__ B, int ldb, long long Bbs,
    int K,
    void* __restrict__ out, int ldo, long long Obs,
    const float* __restrict__ bias,
    const unsigned short* __restrict__ gate, int ldg,
    float scale, int gx,
    const float* __restrict__ bnd, float* __restrict__ stat) {
    __shared__ unsigned short lds[49152];  // X @0, Y @24576
    const int tid = threadIdx.x, lane = tid & 63, wid = tid >> 6;
    const int wr = wid >> 1, wc = wid & 1;
    const int nwg = gridDim.x;
    const int bswz = ((int)blockIdx.x & 7) * (nwg >> 3) + ((int)blockIdx.x >> 3);
    const int bx = bswz % gx, by = bswz / gx;
    const int bm = by * 256, bn = bx * 128;
    const int z = blockIdx.z;
    A += (long long)z * Abs;
    B += (long long)z * Bbs;
    const int NT = K >> 6;

    const int sswz = ((tid & 7) ^ ((tid >> 3) & 7)) * 8;
    size_t agc[4], bgc[2];
#pragma unroll
    for (int c = 0; c < 4; ++c)
        agc[c] = (size_t)(bm + c * 64 + (tid >> 3)) * lda + sswz;
#pragma unroll
    for (int c = 0; c < 2; ++c)
        bgc[c] = (size_t)(bn + c * 64 + (tid >> 3)) * ldb + sswz;
    const int wl = wid * 512;

    auto stA01 = [&](int t, int buf) {
        const size_t k0 = (size_t)t << 6;
        llds16(A + agc[0] + k0, &lds[buf + wl]);
        llds16(A + agc[1] + k0, &lds[buf + 4096 + wl]);
    };
    auto stA23 = [&](int t, int buf) {
        const size_t k0 = (size_t)t << 6;
        llds16(A + agc[2] + k0, &lds[buf + 8192 + wl]);
        llds16(A + agc[3] + k0, &lds[buf + 12288 + wl]);
    };
    auto stB = [&](int t, int buf) {
        const size_t k0 = (size_t)t << 6;
        llds16(B + bgc[0] + k0, &lds[buf + 16384 + wl]);
        llds16(B + bgc[1] + k0, &lds[buf + 20480 + wl]);
    };

    const int l15 = lane & 15, g4 = lane >> 4, l7 = lane & 7;
    const int x0 = (g4 ^ l7) * 8, x1 = ((4 + g4) ^ l7) * 8;
    const int ab = (wr * 64 + l15) * 64;
    const int bbv = 16384 + (wc * 64 + l15) * 64;
    constexpr int X = 0, Y = 24576;

    f32x4 acc[4][4] = {};

    stB(0, X); stA01(0, X); stA23(0, X); stB(1, Y);
    VM4;
    BAR; SCB;

    int t = 0;
    while (true) {
        const bool last = (t + 2) >= NT;
        bf16x8 bf[4][2], af[2][2];
        // ---- F0
#pragma unroll
        for (int j = 0; j < 4; ++j) {
            bf[j][0] = *(const bf16x8*)&lds[X + bbv + j * 1024 + x0];
            bf[j][1] = *(const bf16x8*)&lds[X + bbv + j * 1024 + x1];
        }
#pragma unroll
        for (int i = 0; i < 2; ++i) {
            af[i][0] = *(const bf16x8*)&lds[X + ab + i * 1024 + x0];
            af[i][1] = *(const bf16x8*)&lds[X + ab + i * 1024 + x1];
        }
        stA01(t + 1, Y);
        LGKM0; SCB;
        __builtin_amdgcn_s_setprio(1);
#pragma unroll
        for (int s = 0; s < 2; ++s)
#pragma unroll
            for (int i = 0; i < 2; ++i)
#pragma unroll
                for (int j = 0; j < 4; ++j)
                    acc[i][j] = MF(af[i][s], bf[j][s], acc[i][j]);
        __builtin_amdgcn_s_setprio(0);
        VM4;
        BAR; SCB;
        // ---- F1
#pragma unroll
        for (int i = 0; i < 2; ++i) {
            af[i][0] = *(const bf16x8*)&lds[X + ab + (2 + i) * 1024 + x0];
            af[i][1] = *(const bf16x8*)&lds[X + ab + (2 + i) * 1024 + x1];
        }
        stA23(t + 1, Y);
        if (!last) stB(t + 2, X);
        LGKM0; SCB;
        __builtin_amdgcn_s_setprio(1);
#pragma unroll
        for (int s = 0; s < 2; ++s)
#pragma unroll
            for (int i = 0; i < 2; ++i)
#pragma unroll
                for (int j = 0; j < 4; ++j)
                    acc[2 + i][j] = MF(af[i][s], bf[j][s], acc[2 + i][j]);
        __builtin_amdgcn_s_setprio(0);
        if (last) { VM2; } else { VM4; }
        BAR; SCB;
        // ---- F2
#pragma unroll
        for (int j = 0; j < 4; ++j) {
            bf[j][0] = *(const bf16x8*)&lds[Y + bbv + j * 1024 + x0];
            bf[j][1] = *(const bf16x8*)&lds[Y + bbv + j * 1024 + x1];
        }
#pragma unroll
        for (int i = 0; i < 2; ++i) {
            af[i][0] = *(const bf16x8*)&lds[Y + ab + i * 1024 + x0];
            af[i][1] = *(const bf16x8*)&lds[Y + ab + i * 1024 + x1];
        }
        if (!last) stA01(t + 2, X);
        LGKM0; SCB;
        __builtin_amdgcn_s_setprio(1);
#pragma unroll
        for (int s = 0; s < 2; ++s)
#pragma unroll
            for (int i = 0; i < 2; ++i)
#pragma unroll
                for (int j = 0; j < 4; ++j)
                    acc[i][j] = MF(af[i][s], bf[j][s], acc[i][j]);
        __builtin_amdgcn_s_setprio(0);
        if (last) { VM0; } else { VM4; }
        BAR; SCB;
        // ---- F3
#pragma unroll
        for (int i = 0; i < 2; ++i) {
            af[i][0] = *(const bf16x8*)&lds[Y + ab + (2 + i) * 1024 + x0];
            af[i][1] = *(const bf16x8*)&lds[Y + ab + (2 + i) * 1024 + x1];
        }
        if (!last) { stA23(t + 2, X); stB(t + 3, Y); }
        LGKM0; SCB;
        __builtin_amdgcn_s_setprio(1);
#pragma unroll
        for (int s = 0; s < 2; ++s)
#pragma unroll
            for (int i = 0; i < 2; ++i)
#pragma unroll
                for (int j = 0; j < 4; ++j)
                    acc[2 + i][j] = MF(af[i][s], bf[j][s], acc[2 + i][j]);
        __builtin_amdgcn_s_setprio(0);
        if (last) break;
        VM4;
        BAR; SCB;
        t += 2;
    }

    // --- epilogue
    const int row0 = bm + wr * 64, col0 = bn + wc * 64;
    if constexpr (EPI == 0 || EPI == 1) {
        unsigned short* o = (unsigned short*)out;
#pragma unroll
        for (int i = 0; i < 4; ++i) {
            const int mb = row0 + i * 16 + g4 * 4;
#pragma unroll
            for (int j = 0; j < 4; ++j) {
                const int n = col0 + j * 16 + l15;
                const float bs = bias[n];
#pragma unroll
                for (int q = 0; q < 4; ++q) {
                    float val = acc[i][j][q] + bs;
                    if constexpr (EPI == 0) val = val / (1.f + __expf(-val));
                    o[(size_t)(mb + q) * ldo + n] = f2bf(val);
                }
            }
        }
    } else if constexpr (EPI == 2) {
        unsigned short* o = (unsigned short*)out;
#pragma unroll
        for (int i = 0; i < 4; ++i) {
            const int mb = row0 + i * 16 + g4 * 4;
#pragma unroll
            for (int j = 0; j < 4; ++j) {
                const int n = col0 + j * 16 + l15;
                const float bs = bias[n];
                ushort4 pk;
                unsigned short* pku = (unsigned short*)&pk;
#pragma unroll
                for (int q = 0; q < 4; ++q) {
                    int m = mb + q;
                    float g = bf2f(gate[(size_t)m * ldg + n]);
                    pku[q] = f2bf((acc[i][j][q] + bs) / (1.f + __expf(-g)));
                }
                size_t oi = ((size_t)(mb >> 11) * 1024 + n) * 2048 + (mb & 2047);
                *(ushort4*)(o + oi) = pk;
            }
        }
    } else {  // EPI == 6: gi bf16 = acc / l[row]
        unsigned short* o = (unsigned short*)out + (size_t)z * Obs;
        const float* ls = bnd + (size_t)z * 2048;
#pragma unroll
        for (int i = 0; i < 4; ++i) {
            const int mb = row0 + i * 16 + g4 * 4;
            float invl[4];
#pragma unroll
            for (int q = 0; q < 4; ++q) invl[q] = 1.f / ls[mb + q];
#pragma unroll
            for (int j = 0; j < 4; ++j) {
                const int n = col0 + j * 16 + l15;
#pragma unroll
                for (int q = 0; q < 4; ++q)
                    o[(size_t)(mb + q) * ldo + n] = f2bf(acc[i][j][q] * invl[q]);
            }
        }
    }
}

// ---------------- fused mix + RMSNorm: out f32 [row][1024] ----------------
__global__ __launch_bounds__(256) void mix_rmsnorm(
    const unsigned short* __restrict__ gi, const float* __restrict__ x,
    const float* __restrict__ mixw, const float* __restrict__ normw,
    float* __restrict__ out) {
    const int D = 1024;
    const size_t base = (size_t)blockIdx.x * D;
    const int t = threadIdx.x, lane = t & 63, wid = t >> 6;
    ushort4 g4 = ((const ushort4*)(gi + base))[t];
    float4 xv = ((const float4*)(x + base))[t];
    float4 mw = ((const float4*)mixw)[t];
    float4 v;
    v.x = mw.x * bf2f(g4.x) + (1.f - mw.x) * xv.x;
    v.y = mw.y * bf2f(g4.y) + (1.f - mw.y) * xv.y;
    v.z = mw.z * bf2f(g4.z) + (1.f - mw.z) * xv.z;
    v.w = mw.w * bf2f(g4.w) + (1.f - mw.w) * xv.w;
    float ss = v.x * v.x + v.y * v.y + v.z * v.z + v.w * v.w;
#pragma unroll
    for (int off = 32; off; off >>= 1) ss += __shfl_xor(ss, off);
    __shared__ float red[4];
    if (lane == 0) red[wid] = ss;
    __syncthreads();
    ss = red[0] + red[1] + red[2] + red[3];
    float sc = rsqrtf(ss / (float)D + 1e-6f);
    float4 wv = ((const float4*)normw)[t];
    v.x *= sc * wv.x; v.y *= sc * wv.y; v.z *= sc * wv.z; v.w *= sc * wv.w;
    ((float4*)(out + base))[t] = v;
}

// ---------------------------------------------------------------------------
extern "C" void kernel_launch(void* const* d_in, const int* in_sizes, int n_in,
                              void* d_out, int out_size, void* d_ws, size_t ws_size,
                              hipStream_t stream) {
    const float* x = (const float*)d_in[0];
    const float* W1 = (const float*)d_in[1];
    const float* b1 = (const float*)d_in[2];
    const float* W2 = (const float*)d_in[3];
    const float* b2 = (const float*)d_in[4];
    const float* Wv = (const float*)d_in[5];
    const float* bv = (const float*)d_in[6];
    const float* mixw = (const float*)d_in[7];
    const float* normw = (const float*)d_in[8];
    float* out = (float*)d_out;

    const int L = 2048, D = 1024, INNER = 1536, BN4 = 4;
    const int M = BN4 * L;  // 8192

    // workspace carve
    char* w = (char*)d_ws;
    auto carve = [&](size_t bytes) {
        void* p = (void*)w;
        w += (bytes + 255) & ~(size_t)255;
        return p;
    };
    unsigned short* xbf = (unsigned short*)carve((size_t)M * D * 2);
    unsigned short* w1t = (unsigned short*)carve((size_t)INNER * D * 2);
    unsigned short* w2t = (unsigned short*)carve((size_t)3 * D * INNER * 2);
    unsigned short* wvt = (unsigned short*)carve((size_t)D * D * 2);
    unsigned short* h = (unsigned short*)carve((size_t)M * INNER * 2);
    unsigned short* qkg = (unsigned short*)carve((size_t)M * 3 * D * 2);
    unsigned short* vt = (unsigned short*)carve((size_t)BN4 * D * L * 2);
    unsigned short* pbuf = (unsigned short*)carve((size_t)BN4 * L * L * 2);
    float* lsum = (float*)carve((size_t)M * 4);  // softmax row sums
    unsigned short* gi = h;  // h dead after GEMM2; reuse for gi [B][L][D]

    // 0) zero the row-sum accumulator
    zero_f32<<<M / 256, 256, 0, stream>>>(lsum, M);
    // 1) x -> bf16
    cvt_f32_bf16<<<(M * D) / 2048, 256, 0, stream>>>(x, xbf, (long long)M * D / 8);
    // 2-4) weights -> bf16, transposed to [N][K]
    transpose_cvt<<<dim3(INNER / 32, D / 32), 256, 0, stream>>>(W1, w1t, D, INNER);
    transpose_cvt<<<dim3(3 * D / 32, INNER / 32), 256, 0, stream>>>(W2, w2t, INNER, 3 * D);
    transpose_cvt<<<dim3(D / 32, D / 32), 256, 0, stream>>>(Wv, wvt, D, D);
    // 5) h = silu(x @ W1 + b1)   [M][INNER] bf16  (384 blocks, gx=12)
    gemm5<0><<<dim3(384, 1, 1), 512, 0, stream>>>(
        xbf, D, 0, w1t, D, 0, D, h, INNER, 0, b1, nullptr, 0,
        1.f, 12, nullptr, nullptr);
    // 6) qkg = h @ W2 + b2       [M][3D] bf16  (8-phase 256^2, 384 blocks)
    gemm8<1><<<dim3(384, 1, 1), 512, 0, stream>>>(
        h, INNER, 0, w2t, INNER, 0, INNER, qkg, 3 * D, 0,
        1.f, 12, nullptr, b2);
    // 7) vT = ((x @ Wv + bv)*sigmoid(g))^T  [B][D][L] bf16  (256 blocks)
    gemm5<2><<<dim3(256, 1, 1), 512, 0, stream>>>(
        xbf, D, 0, wvt, D, 0, D, vt, L, 0, bv, qkg + 2 * D, 3 * D,
        1.f, 8, nullptr, nullptr);
    // 8) P' = exp(min(q@k^T/32,80)) bf16 [B][L][L]; row sums -> lsum
    //    8-phase 256x256: 8x8 grid x 4 batches = 256 blocks (1 wave)
    gemm8<5><<<dim3(64, 1, BN4), 512, 0, stream>>>(
        qkg, 3 * D, (long long)L * 3 * D, qkg + D, 3 * D, (long long)L * 3 * D,
        D, pbuf, L, (long long)L * L, 0.03125f, 8, lsum, nullptr);
    // 9) gi = (P' @ vT^T)/l  bf16 [B][L][D]   (256 blocks)
    gemm5<6><<<dim3(64, 1, BN4), 512, 0, stream>>>(
        pbuf, L, (long long)L * L, vt, L, (long long)D * L, L, gi, D,
        (long long)L * D, nullptr, nullptr, 0, 1.f, 8, lsum, nullptr);
    // 10) out = rmsnorm(mix*gi + (1-mix)*x)
    mix_rmsnorm<<<M, 256, 0, stream>>>(gi, x, mixw, normw, out);
}

// Round 12
// 272.826 us; speedup vs baseline: 1.0058x; 1.0058x over previous
//
#include <hip/hip_runtime.h>
#include <hip/hip_bf16.h>
#include <stdint.h>

// ---------------------------------------------------------------------------
// SelectiveMixing: x->W1->silu->W2->(q,k,g); v=(x@Wv+bv)*sig(g);
// attn=softmax(qk^T/sqrt(D)); out=rmsnorm(mix*attn@v + (1-mix)*x)
// B=4, L=2048, D=1024, INNER=1536. bf16 MFMA, f32 accum.
// Softmax fused: P' = exp(min(s,80)) bf16 + f32 row sums (atomics); PV
// applies 1/l; fused mix+rmsnorm finishes.
// gemm8<EPI>: m201-style 8-phase 256x256 GEMM (wave tile 128x64, B
//   reg-cached, counted vmcnt(4) at phases 4/8) — GEMM2 (EPI 1) + scores
//   (EPI 5). gemm5<EPI>: 256x128 4-phase GEMM — GEMM1, VGEMM, PV.
// RULE: inside counted-vmcnt regions NO other VMEM op may issue.
// ---------------------------------------------------------------------------

typedef __bf16 bf16x8 __attribute__((ext_vector_type(8)));
typedef float f32x4 __attribute__((ext_vector_type(4)));

#define VM4 asm volatile("s_waitcnt vmcnt(4)" ::: "memory")
#define VM2 asm volatile("s_waitcnt vmcnt(2)" ::: "memory")
#define VM0 asm volatile("s_waitcnt vmcnt(0)" ::: "memory")
#define LGKM0 asm volatile("s_waitcnt lgkmcnt(0)" ::: "memory")
#define BAR __builtin_amdgcn_s_barrier()
#define SCB __builtin_amdgcn_sched_barrier(0)

__device__ __forceinline__ unsigned short f2bf(float f) {
    unsigned int u = __float_as_uint(f);
    u += 0x7fffu + ((u >> 16) & 1u);
    return (unsigned short)(u >> 16);
}
__device__ __forceinline__ float bf2f(unsigned short s) {
    return __uint_as_float(((unsigned int)s) << 16);
}
__device__ __forceinline__ void llds16(const void* g, void* l) {
    __builtin_amdgcn_global_load_lds(
        (const __attribute__((address_space(1))) void*)g,
        (__attribute__((address_space(3))) void*)l, 16, 0, 0);
}
__device__ __forceinline__ f32x4 MF(bf16x8 a, bf16x8 b, f32x4 c) {
    return __builtin_amdgcn_mfma_f32_16x16x32_bf16(a, b, c, 0, 0, 0);
}

// ---------------- zero fill ------------------------------------------------
__global__ __launch_bounds__(256) void zero_f32(float* __restrict__ p, int n) {
    int i = blockIdx.x * 256 + threadIdx.x;
    if (i < n) p[i] = 0.f;
}

// ---------------- elementwise: f32 -> bf16 (8 elems/thread) ----------------
__global__ __launch_bounds__(256) void cvt_f32_bf16(
    const float* __restrict__ in, unsigned short* __restrict__ out, long long n8) {
    long long i = (long long)blockIdx.x * 256 + threadIdx.x;
    if (i >= n8) return;
    float4 a = ((const float4*)in)[2 * i];
    float4 b = ((const float4*)in)[2 * i + 1];
    ushort4 p0, p1;
    p0.x = f2bf(a.x); p0.y = f2bf(a.y); p0.z = f2bf(a.z); p0.w = f2bf(a.w);
    p1.x = f2bf(b.x); p1.y = f2bf(b.y); p1.z = f2bf(b.z); p1.w = f2bf(b.w);
    ((ushort4*)out)[2 * i] = p0;
    ((ushort4*)out)[2 * i + 1] = p1;
}

// ---------------- transpose + convert: f32 [R][C] -> bf16 [C][R] -----------
__global__ __launch_bounds__(256) void transpose_cvt(
    const float* __restrict__ in, unsigned short* __restrict__ out, int R, int C) {
    __shared__ unsigned short tile[32][33];
    int c0 = blockIdx.x * 32, r0 = blockIdx.y * 32;
    int cc = threadIdx.x & 31, rr = threadIdx.x >> 5;
#pragma unroll
    for (int p = 0; p < 4; ++p) {
        int r = rr + p * 8;
        tile[r][cc] = f2bf(in[(size_t)(r0 + r) * C + c0 + cc]);
    }
    __syncthreads();
#pragma unroll
    for (int p = 0; p < 4; ++p) {
        int c = rr + p * 8;
        out[(size_t)(c0 + c) * R + r0 + cc] = tile[cc][c];
    }
}

// ---------------- gemm8: 8-phase 256x256 GEMM, C = A @ B^T -----------------
// 512 threads = 8 waves (2M x 4N), wave tile 128x64, BK=64.
// LDS: 2 buffers x (A 256x64 + B 256x64) bf16 = 128 KiB, XOR-swizzled.
// Per K-tile: 4 phases; phase q reads A M-frags {2q,2q+1}; at q==0 all 8 B
// frags (reg-cached for the tile). Each phase stages one half-tile per the
// FIFO ledger (see round-8 comment). vmcnt(4) at phase 4/8 end; last
// iteration: vmcnt(0) at phase 4, nothing outstanding at phase 8.
// EPI 1: bf16 = acc + bias[n]
// EPI 5: P' bf16 = exp(min(acc*scale,80)); atomicAdd row sums into stat.
template <int EPI>
__global__ __launch_bounds__(512, 1) void gemm8(
    const unsigned short* __restrict__ A, int lda, long long Abs,
    const unsigned short* __restrict__ B, int ldb, long long Bbs,
    int K,
    unsigned short* __restrict__ out, int ldo, long long Obs,
    float scale, int gx, float* __restrict__ stat,
    const float* __restrict__ bias) {
    __shared__ unsigned short lds[65536];  // X @0, Y @32768
    const int tid = threadIdx.x, lane = tid & 63, wid = tid >> 6;
    const int wr = wid >> 2, wc = wid & 3;  // 2M x 4N
    const int nwg = gridDim.x;
    const int bswz = ((int)blockIdx.x & 7) * (nwg >> 3) + ((int)blockIdx.x >> 3);
    const int bx = bswz % gx, by = bswz / gx;
    const int bm = by * 256, bn = bx * 256;
    const int z = blockIdx.z;
    A += (long long)z * Abs;
    B += (long long)z * Bbs;
    const int NT = K >> 6;  // even, >= 4

    const int sswz = ((tid & 7) ^ ((tid >> 3) & 7)) * 8;
    size_t agc[4], bgc[4];
#pragma unroll
    for (int c = 0; c < 4; ++c) {
        agc[c] = (size_t)(bm + c * 64 + (tid >> 3)) * lda + sswz;
        bgc[c] = (size_t)(bn + c * 64 + (tid >> 3)) * ldb + sswz;
    }
    const int wl = wid * 512;

    auto stA = [&](int t, int h, int buf) {
        const size_t k0 = (size_t)t << 6;
        llds16(A + agc[h * 2] + k0, &lds[buf + (h * 2) * 4096 + wl]);
        llds16(A + agc[h * 2 + 1] + k0, &lds[buf + (h * 2 + 1) * 4096 + wl]);
    };
    auto stB = [&](int t, int h, int buf) {
        const size_t k0 = (size_t)t << 6;
        llds16(B + bgc[h * 2] + k0, &lds[buf + 16384 + (h * 2) * 4096 + wl]);
        llds16(B + bgc[h * 2 + 1] + k0,
               &lds[buf + 16384 + (h * 2 + 1) * 4096 + wl]);
    };

    const int l15 = lane & 15, g4 = lane >> 4, l7 = lane & 7;
    const int x0 = (g4 ^ l7) * 8, x1 = ((4 + g4) ^ l7) * 8;
    const int ab = (wr * 128 + l15) * 64;           // A: + m*1024 + xs
    const int bbv = 16384 + (wc * 64 + l15) * 64;   // B: + j*1024 + xs
    constexpr int X = 0, Y = 32768;

    f32x4 acc[8][4] = {};

    // prologue: A(0),B(0) -> X; B(1) -> Y. vmcnt(4) leaves B(1) in flight.
    stA(0, 0, X); stA(0, 1, X); stB(0, 0, X); stB(0, 1, X);
    stB(1, 0, Y); stB(1, 1, Y);
    VM4;
    BAR; SCB;

    int t = 0;
    while (true) {
        const bool st2 = (t + 2) < NT;
#pragma unroll
        for (int hb = 0; hb < 2; ++hb) {
            const int buf = hb ? Y : X;
            bf16x8 bfr[4][2];
#pragma unroll
            for (int q = 0; q < 4; ++q) {
                // ---- ds reads for this phase
                if (q == 0) {
#pragma unroll
                    for (int j = 0; j < 4; ++j) {
                        bfr[j][0] = *(const bf16x8*)&lds[buf + bbv + j * 1024 + x0];
                        bfr[j][1] = *(const bf16x8*)&lds[buf + bbv + j * 1024 + x1];
                    }
                }
                bf16x8 af[2][2];
#pragma unroll
                for (int mq = 0; mq < 2; ++mq) {
                    af[mq][0] =
                        *(const bf16x8*)&lds[buf + ab + (q * 2 + mq) * 1024 + x0];
                    af[mq][1] =
                        *(const bf16x8*)&lds[buf + ab + (q * 2 + mq) * 1024 + x1];
                }
                // ---- stage one half-tile (FIFO ledger)
                if (hb == 0) {
                    if (q == 0) stA(t + 1, 0, Y);
                    else if (q == 1) stA(t + 1, 1, Y);
                    else if (q == 2) { if (st2) stB(t + 2, 0, X); }
                    else { if (st2) stB(t + 2, 1, X); }
                } else {
                    if (q == 0) { if (st2) stA(t + 2, 0, X); }
                    else if (q == 1) { if (st2) stA(t + 2, 1, X); }
                    else if (q == 2) { if (st2) stB(t + 3, 0, Y); }
                    else { if (st2) stB(t + 3, 1, Y); }
                }
                BAR;
                LGKM0; SCB;
                __builtin_amdgcn_s_setprio(1);
#pragma unroll
                for (int s = 0; s < 2; ++s)
#pragma unroll
                    for (int mq = 0; mq < 2; ++mq)
#pragma unroll
                        for (int j = 0; j < 4; ++j)
                            acc[q * 2 + mq][j] =
                                MF(af[mq][s], bfr[j][s], acc[q * 2 + mq][j]);
                __builtin_amdgcn_s_setprio(0);
                if (q == 3) {
                    if (hb == 0) { if (st2) { VM4; } else { VM0; } }
                    else if (st2) { VM4; }
                }
                if (hb == 1 && q == 3 && !st2) break;  // done; nothing in flight
                BAR; SCB;
            }
        }
        if (!st2) break;
        t += 2;
    }

    // --- epilogue (all global reads AFTER the final "memory" asm)
    const int row0 = bm + wr * 128, col0 = bn + wc * 64;
    unsigned short* o = out + (size_t)z * Obs;
    if constexpr (EPI == 1) {
#pragma unroll
        for (int m = 0; m < 8; ++m) {
            const int mb = row0 + m * 16 + g4 * 4;
#pragma unroll
            for (int j = 0; j < 4; ++j) {
                const int n = col0 + j * 16 + l15;
                const float bs = bias[n];
#pragma unroll
                for (int qq = 0; qq < 4; ++qq)
                    o[(size_t)(mb + qq) * ldo + n] = f2bf(acc[m][j][qq] + bs);
            }
        }
    } else {  // EPI == 5
#pragma unroll
        for (int m = 0; m < 8; ++m) {
            const int mb = row0 + m * 16 + g4 * 4;
            float rs[4] = {0.f, 0.f, 0.f, 0.f};
#pragma unroll
            for (int j = 0; j < 4; ++j) {
                const int n = col0 + j * 16 + l15;
#pragma unroll
                for (int qq = 0; qq < 4; ++qq) {
                    float p = __expf(fminf(acc[m][j][qq] * scale, 80.f));
                    o[(size_t)(mb + qq) * ldo + n] = f2bf(p);
                    rs[qq] += p;
                }
            }
#pragma unroll
            for (int qq = 0; qq < 4; ++qq) {
                float s = rs[qq];
                s += __shfl_xor(s, 1); s += __shfl_xor(s, 2);
                s += __shfl_xor(s, 4); s += __shfl_xor(s, 8);
                if (l15 == 0) atomicAdd(&stat[(size_t)z * 2048 + mb + qq], s);
            }
        }
    }
}

// ---------------- gemm5: 256x128 pipelined GEMM, C = A @ B^T ---------------
// EPI 1: bf16 = acc+bias[n]
// EPI 0: bf16 = silu(acc+bias[n])
// EPI 2: vT bf16: out[(m>>11)*1024+n][m&2047] = (acc+bias[n])*sigmoid(gate)
// EPI 6: gi bf16 = acc / l[row]
template <int EPI>
__global__ __launch_bounds__(512, 1) void gemm5(
    const unsigned short* __restrict__ A, int lda, long long Abs,
    const unsigned short* __restrict__ B, int ldb, long long Bbs,
    int K,
    void* __restrict__ out, int ldo, long long Obs,
    const float* __restrict__ bias,
    const unsigned short* __restrict__ gate, int ldg,
    float scale, int gx,
    const float* __restrict__ bnd, float* __restrict__ stat) {
    __shared__ unsigned short lds[49152];  // X @0, Y @24576
    const int tid = threadIdx.x, lane = tid & 63, wid = tid >> 6;
    const int wr = wid >> 1, wc = wid & 1;
    const int nwg = gridDim.x;
    const int bswz = ((int)blockIdx.x & 7) * (nwg >> 3) + ((int)blockIdx.x >> 3);
    const int bx = bswz % gx, by = bswz / gx;
    const int bm = by * 256, bn = bx * 128;
    const int z = blockIdx.z;
    A += (long long)z * Abs;
    B += (long long)z * Bbs;
    const int NT = K >> 6;

    const int sswz = ((tid & 7) ^ ((tid >> 3) & 7)) * 8;
    size_t agc[4], bgc[2];
#pragma unroll
    for (int c = 0; c < 4; ++c)
        agc[c] = (size_t)(bm + c * 64 + (tid >> 3)) * lda + sswz;
#pragma unroll
    for (int c = 0; c < 2; ++c)
        bgc[c] = (size_t)(bn + c * 64 + (tid >> 3)) * ldb + sswz;
    const int wl = wid * 512;

    auto stA01 = [&](int t, int buf) {
        const size_t k0 = (size_t)t << 6;
        llds16(A + agc[0] + k0, &lds[buf + wl]);
        llds16(A + agc[1] + k0, &lds[buf + 4096 + wl]);
    };
    auto stA23 = [&](int t, int buf) {
        const size_t k0 = (size_t)t << 6;
        llds16(A + agc[2] + k0, &lds[buf + 8192 + wl]);
        llds16(A + agc[3] + k0, &lds[buf + 12288 + wl]);
    };
    auto stB = [&](int t, int buf) {
        const size_t k0 = (size_t)t << 6;
        llds16(B + bgc[0] + k0, &lds[buf + 16384 + wl]);
        llds16(B + bgc[1] + k0, &lds[buf + 20480 + wl]);
    };

    const int l15 = lane & 15, g4 = lane >> 4, l7 = lane & 7;
    const int x0 = (g4 ^ l7) * 8, x1 = ((4 + g4) ^ l7) * 8;
    const int ab = (wr * 64 + l15) * 64;
    const int bbv = 16384 + (wc * 64 + l15) * 64;
    constexpr int X = 0, Y = 24576;

    f32x4 acc[4][4] = {};

    stB(0, X); stA01(0, X); stA23(0, X); stB(1, Y);
    VM4;
    BAR; SCB;

    int t = 0;
    while (true) {
        const bool last = (t + 2) >= NT;
        bf16x8 bf[4][2], af[2][2];
        // ---- F0
#pragma unroll
        for (int j = 0; j < 4; ++j) {
            bf[j][0] = *(const bf16x8*)&lds[X + bbv + j * 1024 + x0];
            bf[j][1] = *(const bf16x8*)&lds[X + bbv + j * 1024 + x1];
        }
#pragma unroll
        for (int i = 0; i < 2; ++i) {
            af[i][0] = *(const bf16x8*)&lds[X + ab + i * 1024 + x0];
            af[i][1] = *(const bf16x8*)&lds[X + ab + i * 1024 + x1];
        }
        stA01(t + 1, Y);
        LGKM0; SCB;
        __builtin_amdgcn_s_setprio(1);
#pragma unroll
        for (int s = 0; s < 2; ++s)
#pragma unroll
            for (int i = 0; i < 2; ++i)
#pragma unroll
                for (int j = 0; j < 4; ++j)
                    acc[i][j] = MF(af[i][s], bf[j][s], acc[i][j]);
        __builtin_amdgcn_s_setprio(0);
        VM4;
        BAR; SCB;
        // ---- F1
#pragma unroll
        for (int i = 0; i < 2; ++i) {
            af[i][0] = *(const bf16x8*)&lds[X + ab + (2 + i) * 1024 + x0];
            af[i][1] = *(const bf16x8*)&lds[X + ab + (2 + i) * 1024 + x1];
        }
        stA23(t + 1, Y);
        if (!last) stB(t + 2, X);
        LGKM0; SCB;
        __builtin_amdgcn_s_setprio(1);
#pragma unroll
        for (int s = 0; s < 2; ++s)
#pragma unroll
            for (int i = 0; i < 2; ++i)
#pragma unroll
                for (int j = 0; j < 4; ++j)
                    acc[2 + i][j] = MF(af[i][s], bf[j][s], acc[2 + i][j]);
        __builtin_amdgcn_s_setprio(0);
        if (last) { VM2; } else { VM4; }
        BAR; SCB;
        // ---- F2
#pragma unroll
        for (int j = 0; j < 4; ++j) {
            bf[j][0] = *(const bf16x8*)&lds[Y + bbv + j * 1024 + x0];
            bf[j][1] = *(const bf16x8*)&lds[Y + bbv + j * 1024 + x1];
        }
#pragma unroll
        for (int i = 0; i < 2; ++i) {
            af[i][0] = *(const bf16x8*)&lds[Y + ab + i * 1024 + x0];
            af[i][1] = *(const bf16x8*)&lds[Y + ab + i * 1024 + x1];
        }
        if (!last) stA01(t + 2, X);
        LGKM0; SCB;
        __builtin_amdgcn_s_setprio(1);
#pragma unroll
        for (int s = 0; s < 2; ++s)
#pragma unroll
            for (int i = 0; i < 2; ++i)
#pragma unroll
                for (int j = 0; j < 4; ++j)
                    acc[i][j] = MF(af[i][s], bf[j][s], acc[i][j]);
        __builtin_amdgcn_s_setprio(0);
        if (last) { VM0; } else { VM4; }
        BAR; SCB;
        // ---- F3
#pragma unroll
        for (int i = 0; i < 2; ++i) {
            af[i][0] = *(const bf16x8*)&lds[Y + ab + (2 + i) * 1024 + x0];
            af[i][1] = *(const bf16x8*)&lds[Y + ab + (2 + i) * 1024 + x1];
        }
        if (!last) { stA23(t + 2, X); stB(t + 3, Y); }
        LGKM0; SCB;
        __builtin_amdgcn_s_setprio(1);
#pragma unroll
        for (int s = 0; s < 2; ++s)
#pragma unroll
            for (int i = 0; i < 2; ++i)
#pragma unroll
                for (int j = 0; j < 4; ++j)
                    acc[2 + i][j] = MF(af[i][s], bf[j][s], acc[2 + i][j]);
        __builtin_amdgcn_s_setprio(0);
        if (last) break;
        VM4;
        BAR; SCB;
        t += 2;
    }

    // --- epilogue
    const int row0 = bm + wr * 64, col0 = bn + wc * 64;
    if constexpr (EPI == 0 || EPI == 1) {
        unsigned short* o = (unsigned short*)out;
#pragma unroll
        for (int i = 0; i < 4; ++i) {
            const int mb = row0 + i * 16 + g4 * 4;
#pragma unroll
            for (int j = 0; j < 4; ++j) {
                const int n = col0 + j * 16 + l15;
                const float bs = bias[n];
#pragma unroll
                for (int q = 0; q < 4; ++q) {
                    float val = acc[i][j][q] + bs;
                    if constexpr (EPI == 0) val = val / (1.f + __expf(-val));
                    o[(size_t)(mb + q) * ldo + n] = f2bf(val);
                }
            }
        }
    } else if constexpr (EPI == 2) {
        unsigned short* o = (unsigned short*)out;
#pragma unroll
        for (int i = 0; i < 4; ++i) {
            const int mb = row0 + i * 16 + g4 * 4;
#pragma unroll
            for (int j = 0; j < 4; ++j) {
                const int n = col0 + j * 16 + l15;
                const float bs = bias[n];
                ushort4 pk;
                unsigned short* pku = (unsigned short*)&pk;
#pragma unroll
                for (int q = 0; q < 4; ++q) {
                    int m = mb + q;
                    float g = bf2f(gate[(size_t)m * ldg + n]);
                    pku[q] = f2bf((acc[i][j][q] + bs) / (1.f + __expf(-g)));
                }
                size_t oi = ((size_t)(mb >> 11) * 1024 + n) * 2048 + (mb & 2047);
                *(ushort4*)(o + oi) = pk;
            }
        }
    } else {  // EPI == 6: gi bf16 = acc / l[row]
        unsigned short* o = (unsigned short*)out + (size_t)z * Obs;
        const float* ls = bnd + (size_t)z * 2048;
#pragma unroll
        for (int i = 0; i < 4; ++i) {
            const int mb = row0 + i * 16 + g4 * 4;
            float invl[4];
#pragma unroll
            for (int q = 0; q < 4; ++q) invl[q] = 1.f / ls[mb + q];
#pragma unroll
            for (int j = 0; j < 4; ++j) {
                const int n = col0 + j * 16 + l15;
#pragma unroll
                for (int q = 0; q < 4; ++q)
                    o[(size_t)(mb + q) * ldo + n] = f2bf(acc[i][j][q] * invl[q]);
            }
        }
    }
}

// ---------------- fused mix + RMSNorm: out f32 [row][1024] ----------------
__global__ __launch_bounds__(256) void mix_rmsnorm(
    const unsigned short* __restrict__ gi, const float* __restrict__ x,
    const float* __restrict__ mixw, const float* __restrict__ normw,
    float* __restrict__ out) {
    const int D = 1024;
    const size_t base = (size_t)blockIdx.x * D;
    const int t = threadIdx.x, lane = t & 63, wid = t >> 6;
    ushort4 g4 = ((const ushort4*)(gi + base))[t];
    float4 xv = ((const float4*)(x + base))[t];
    float4 mw = ((const float4*)mixw)[t];
    float4 v;
    v.x = mw.x * bf2f(g4.x) + (1.f - mw.x) * xv.x;
    v.y = mw.y * bf2f(g4.y) + (1.f - mw.y) * xv.y;
    v.z = mw.z * bf2f(g4.z) + (1.f - mw.z) * xv.z;
    v.w = mw.w * bf2f(g4.w) + (1.f - mw.w) * xv.w;
    float ss = v.x * v.x + v.y * v.y + v.z * v.z + v.w * v.w;
#pragma unroll
    for (int off = 32; off; off >>= 1) ss += __shfl_xor(ss, off);
    __shared__ float red[4];
    if (lane == 0) red[wid] = ss;
    __syncthreads();
    ss = red[0] + red[1] + red[2] + red[3];
    float sc = rsqrtf(ss / (float)D + 1e-6f);
    float4 wv = ((const float4*)normw)[t];
    v.x *= sc * wv.x; v.y *= sc * wv.y; v.z *= sc * wv.z; v.w *= sc * wv.w;
    ((float4*)(out + base))[t] = v;
}

// ---------------------------------------------------------------------------
extern "C" void kernel_launch(void* const* d_in, const int* in_sizes, int n_in,
                              void* d_out, int out_size, void* d_ws, size_t ws_size,
                              hipStream_t stream) {
    const float* x = (const float*)d_in[0];
    const float* W1 = (const float*)d_in[1];
    const float* b1 = (const float*)d_in[2];
    const float* W2 = (const float*)d_in[3];
    const float* b2 = (const float*)d_in[4];
    const float* Wv = (const float*)d_in[5];
    const float* bv = (const float*)d_in[6];
    const float* mixw = (const float*)d_in[7];
    const float* normw = (const float*)d_in[8];
    float* out = (float*)d_out;

    const int L = 2048, D = 1024, INNER = 1536, BN4 = 4;
    const int M = BN4 * L;  // 8192

    // workspace carve
    char* w = (char*)d_ws;
    auto carve = [&](size_t bytes) {
        void* p = (void*)w;
        w += (bytes + 255) & ~(size_t)255;
        return p;
    };
    unsigned short* xbf = (unsigned short*)carve((size_t)M * D * 2);
    unsigned short* w1t = (unsigned short*)carve((size_t)INNER * D * 2);
    unsigned short* w2t = (unsigned short*)carve((size_t)3 * D * INNER * 2);
    unsigned short* wvt = (unsigned short*)carve((size_t)D * D * 2);
    unsigned short* h = (unsigned short*)carve((size_t)M * INNER * 2);
    unsigned short* qkg = (unsigned short*)carve((size_t)M * 3 * D * 2);
    unsigned short* vt = (unsigned short*)carve((size_t)BN4 * D * L * 2);
    unsigned short* pbuf = (unsigned short*)carve((size_t)BN4 * L * L * 2);
    float* lsum = (float*)carve((size_t)M * 4);  // softmax row sums
    unsigned short* gi = h;  // h dead after GEMM2; reuse for gi [B][L][D]

    // 0) zero the row-sum accumulator
    zero_f32<<<M / 256, 256, 0, stream>>>(lsum, M);
    // 1) x -> bf16
    cvt_f32_bf16<<<(M * D) / 2048, 256, 0, stream>>>(x, xbf, (long long)M * D / 8);
    // 2-4) weights -> bf16, transposed to [N][K]
    transpose_cvt<<<dim3(INNER / 32, D / 32), 256, 0, stream>>>(W1, w1t, D, INNER);
    transpose_cvt<<<dim3(3 * D / 32, INNER / 32), 256, 0, stream>>>(W2, w2t, INNER, 3 * D);
    transpose_cvt<<<dim3(D / 32, D / 32), 256, 0, stream>>>(Wv, wvt, D, D);
    // 5) h = silu(x @ W1 + b1)   [M][INNER] bf16  (384 blocks, gx=12)
    gemm5<0><<<dim3(384, 1, 1), 512, 0, stream>>>(
        xbf, D, 0, w1t, D, 0, D, h, INNER, 0, b1, nullptr, 0,
        1.f, 12, nullptr, nullptr);
    // 6) qkg = h @ W2 + b2       [M][3D] bf16  (8-phase 256^2, 384 blocks)
    gemm8<1><<<dim3(384, 1, 1), 512, 0, stream>>>(
        h, INNER, 0, w2t, INNER, 0, INNER, qkg, 3 * D, 0,
        1.f, 12, nullptr, b2);
    // 7) vT = ((x @ Wv + bv)*sigmoid(g))^T  [B][D][L] bf16  (256 blocks)
    gemm5<2><<<dim3(256, 1, 1), 512, 0, stream>>>(
        xbf, D, 0, wvt, D, 0, D, vt, L, 0, bv, qkg + 2 * D, 3 * D,
        1.f, 8, nullptr, nullptr);
    // 8) P' = exp(min(q@k^T/32,80)) bf16 [B][L][L]; row sums -> lsum
    //    8-phase 256x256: 8x8 grid x 4 batches = 256 blocks (1 wave)
    gemm8<5><<<dim3(64, 1, BN4), 512, 0, stream>>>(
        qkg, 3 * D, (long long)L * 3 * D, qkg + D, 3 * D, (long long)L * 3 * D,
        D, pbuf, L, (long long)L * L, 0.03125f, 8, lsum, nullptr);
    // 9) gi = (P' @ vT^T)/l  bf16 [B][L][D]   (256 blocks)
    gemm5<6><<<dim3(64, 1, BN4), 512, 0, stream>>>(
        pbuf, L, (long long)L * L, vt, L, (long long)D * L, L, gi, D,
        (long long)L * D, nullptr, nullptr, 0, 1.f, 8, lsum, nullptr);
    // 10) out = rmsnorm(mix*gi + (1-mix)*x)
    mix_rmsnorm<<<M, 256, 0, stream>>>(gi, x, mixw, normw, out);
}